// Round 1
// baseline (34.236 us; speedup 1.0000x reference)
//
#include <hip/hip_runtime.h>
#include <math.h>

#define SDF_INF 1e12f

// ---------------------------------------------------------------------------
// Kernel 1: exact 1-D squared EDT along W (last axis) for BOTH masks (fg, bg).
// One wave (64 lanes) per row of 512. Binary input => nearest-seed distance
// via ballot + clz/ctz sweeps, O(L) total instead of O(L^2).
// ---------------------------------------------------------------------------
__global__ __launch_bounds__(64)
void sdf_rowpass(const float* __restrict__ mask,
                 float* __restrict__ gfg,
                 float* __restrict__ gbg)
{
    const int r = blockIdx.x;            // row id: b*512 + y
    const int lane = threadIdx.x;        // 0..63
    const size_t rbase = (size_t)r * 512;

    // 8 chunks of 64 cover the 512-wide row; one ballot per chunk.
    unsigned long long bal[8];
#pragma unroll
    for (int c = 0; c < 8; ++c) {
        float m = mask[rbase + c * 64 + lane];
        bal[c] = __ballot(m == 1.0f);
    }

#pragma unroll
    for (int pass = 0; pass < 2; ++pass) {
        float* gout = (pass == 0) ? gfg : gbg;
        int dl[8];
        int carry = -(1 << 20);          // "no seed yet" sentinel (far left)
        // left-to-right: nearest seed at position <= p
#pragma unroll
        for (int c = 0; c < 8; ++c) {
            unsigned long long b = (pass == 0) ? bal[c] : ~bal[c];
            unsigned long long le = b & (~0ull >> (63 - lane));  // seeds at <= lane
            int p = c * 64 + lane;
            int nl = le ? (c * 64 + (63 - __builtin_clzll(le))) : carry;
            dl[c] = p - nl;
            carry = b ? (c * 64 + (63 - __builtin_clzll(b))) : carry;
        }
        // right-to-left: nearest seed at position >= p; combine + write
        int carry_r = (1 << 20);         // "no seed yet" sentinel (far right)
#pragma unroll
        for (int c = 7; c >= 0; --c) {
            unsigned long long b = (pass == 0) ? bal[c] : ~bal[c];
            unsigned long long ge = b >> lane;                   // seeds at >= lane
            int p = c * 64 + lane;
            int nr = ge ? (p + (int)__builtin_ctzll(ge)) : carry_r;
            int d = min(dl[c], nr - p);
            // d <= 511 when a seed exists in the row; sentinel => exactly 1e12
            // (matches reference: min_j INF + (i-j)^2 attains INF at j=i).
            float g = (d > 1000) ? SDF_INF : (float)(d * d);
            gout[rbase + p] = g;
            carry_r = b ? (c * 64 + (int)__builtin_ctzll(b)) : carry_r;
        }
    }
}

// ---------------------------------------------------------------------------
// Kernel 2: min-plus along H (general f) + finalize.
// One block per (b, x) column, 512 threads = one output y each.
// Key pruning: at an fg pixel the fg-EDT is exactly 0, so only the bg field
// is needed there (and vice versa) -> each thread scans ONE 512-entry LDS
// column. 4 independent min accumulators break the fmin dependence chain.
// ---------------------------------------------------------------------------
__global__ __launch_bounds__(512)
void sdf_colpass(const float* __restrict__ mask,
                 const float* __restrict__ gfg,
                 const float* __restrict__ gbg,
                 float* __restrict__ out)
{
    __shared__ __align__(16) float colfg[512];
    __shared__ __align__(16) float colbg[512];
    const int colid = blockIdx.x;        // b*512 + x
    const int y = threadIdx.x;           // 0..511
    const int b = colid >> 9;
    const int x = colid & 511;
    const size_t base = ((size_t)b * 512 + y) * 512 + x;   // element (b, y, x)

    colfg[y] = gfg[base];
    colbg[y] = gbg[base];
    const bool fg = (mask[base] == 1.0f);
    __syncthreads();

    const float* colsel = fg ? colbg : colfg;   // 2 distinct LDS addrs/wave: free
    const float yf = (float)y;
    float b0 = SDF_INF, b1 = SDF_INF, b2 = SDF_INF, b3 = SDF_INF;
    for (int j = 0; j < 512; j += 4) {
        float4 g4 = *reinterpret_cast<const float4*>(colsel + j);
        float dy0 = yf - (float)j;
        float dy1 = dy0 - 1.0f;
        float dy2 = dy0 - 2.0f;
        float dy3 = dy0 - 3.0f;
        b0 = fminf(b0, fmaf(dy0, dy0, g4.x));
        b1 = fminf(b1, fmaf(dy1, dy1, g4.y));
        b2 = fminf(b2, fmaf(dy2, dy2, g4.z));
        b3 = fminf(b3, fmaf(dy3, dy3, g4.w));
    }
    float best = fminf(fminf(b0, b1), fminf(b2, b3));
    float dist = sqrtf(best);
    out[base] = fg ? -dist : dist;       // fg: -pos (neg==0); bg: +neg (pos==0)
}

extern "C" void kernel_launch(void* const* d_in, const int* in_sizes, int n_in,
                              void* d_out, int out_size, void* d_ws, size_t ws_size,
                              hipStream_t stream) {
    const float* mask = (const float*)d_in[0];
    float* out = (float*)d_out;
    const int total = in_sizes[0];       // B*512*512
    const int nrows = total / 512;       // B*512 (== #columns too)

    float* gfg = (float*)d_ws;
    float* gbg = gfg + total;            // 2 * total * 4 bytes of scratch

    sdf_rowpass<<<nrows, 64, 0, stream>>>(mask, gfg, gbg);
    sdf_colpass<<<nrows, 512, 0, stream>>>(mask, gfg, gbg, out);
}

// Round 2
// 15.644 us; speedup vs baseline: 2.1885x; 2.1885x over previous
//
#include <hip/hip_runtime.h>
#include <math.h>

// ---------------------------------------------------------------------------
// Kernel 1: exact 1-D row EDT (both classes) via ballot + clz/ctz, O(L).
// One wave per 512-px row; 4 rows per 256-thread block.
// Output: packed u32 per pixel, lo16 = dist-to-nearest-fg, hi16 = dist-to-bg.
// (dfg==0 <=> pixel is fg.)  Sentinel (class absent in row) clamps to 0x7FFF.
// ---------------------------------------------------------------------------
__global__ __launch_bounds__(256)
void sdf_rowpass(const float* __restrict__ mask, unsigned int* __restrict__ packed)
{
    const int r = blockIdx.x * 4 + (threadIdx.x >> 6);   // row id: b*512 + y
    const int lane = threadIdx.x & 63;
    const size_t rbase = (size_t)r * 512;

    unsigned long long bal[8];
#pragma unroll
    for (int c = 0; c < 8; ++c) {
        float m = mask[rbase + c * 64 + lane];
        bal[c] = __ballot(m == 1.0f);
    }

    int dfg[8], dbg[8];
#pragma unroll
    for (int pass = 0; pass < 2; ++pass) {
        int* dd = pass ? dbg : dfg;
        int carry = -(1 << 20);                          // no seed yet (left)
#pragma unroll
        for (int c = 0; c < 8; ++c) {
            unsigned long long b = pass ? ~bal[c] : bal[c];
            unsigned long long le = b & (~0ull >> (63 - lane));
            int p = c * 64 + lane;
            int nl = le ? (c * 64 + (63 - __builtin_clzll(le))) : carry;
            dd[c] = p - nl;
            carry = b ? (c * 64 + (63 - __builtin_clzll(b))) : carry;
        }
        int carry_r = (1 << 20);                         // no seed yet (right)
#pragma unroll
        for (int c = 7; c >= 0; --c) {
            unsigned long long b = pass ? ~bal[c] : bal[c];
            unsigned long long ge = b >> lane;
            int p = c * 64 + lane;
            int nr = ge ? (p + (int)__builtin_ctzll(ge)) : carry_r;
            int d = min(dd[c], nr - p);
            dd[c] = min(d, 32767);                       // sentinel clamp
            carry_r = b ? (c * 64 + (int)__builtin_ctzll(b)) : carry_r;
        }
    }
#pragma unroll
    for (int c = 0; c < 8; ++c)
        packed[rbase + c * 64 + lane] =
            (unsigned)dfg[c] | ((unsigned)dbg[c] << 16);
}

// ---------------------------------------------------------------------------
// Kernel 2: column min-plus + finalize, tiled for coalescing.
// Block = 16 columns x 128 rows (+32-row halo each side). All global reads
// and the output write are 64B-line coalesced (16 cols * 4B = one line).
// Per pixel: exact outward windowed scan with early exit (off^2 >= best);
// expected ~3 iters for a 50% random mask. Exact global fallback if the
// window would exceed the halo (worst-case correctness).
// ---------------------------------------------------------------------------
#define CP_COLS   16
#define CP_YCHUNK 128
#define CP_HALO   32
#define CP_ROWS   (CP_YCHUNK + 2 * CP_HALO)   // 192
#define CP_LDSTR  17                          // pad: kills bank aliasing

__global__ __launch_bounds__(256)
void sdf_colpass(const unsigned int* __restrict__ packed, float* __restrict__ out)
{
    __shared__ unsigned int tile[CP_ROWS * CP_LDSTR];

    const int strip  = blockIdx.x >> 2;       // 16-col strip id (b*32 + xs)
    const int ychunk = blockIdx.x & 3;
    const int b  = strip >> 5;
    const int x0 = (strip & 31) * CP_COLS;
    const int y0 = ychunk * CP_YCHUNK;

    const int c  = threadIdx.x & 15;          // column within strip
    const int rg = threadIdx.x >> 4;          // 0..15

    // ---- stage tile + halo (coalesced: 16 cols * 4B = 64B per row) ----
#pragma unroll
    for (int k = 0; k < CP_ROWS / 16; ++k) {  // 12 rows per thread
        int rr = rg + k * 16;                 // local row 0..191
        int gy = y0 - CP_HALO + rr;
        unsigned v = 0x7FFF7FFFu;             // outside image: both huge
        if (gy >= 0 && gy < 512)
            v = packed[((size_t)b * 512 + gy) * 512 + x0 + c];
        tile[rr * CP_LDSTR + c] = v;
    }
    __syncthreads();

    // ---- per-pixel windowed scan (8 pixels per thread) ----
#pragma unroll
    for (int k = 0; k < CP_YCHUNK / 16; ++k) {
        int yc   = rg + k * 16;               // row within chunk 0..127
        int yloc = yc + CP_HALO;              // local row 32..159
        unsigned pk = tile[yloc * CP_LDSTR + c];
        int dfg = pk & 0xffff;
        bool fg = (dfg == 0);
        int shift = fg ? 16 : 0;
        int dsel = (pk >> shift) & 0xffff;
        int best = dsel * dsel;

        int off = 1;
        for (; off <= CP_HALO; ++off) {
            int o2 = off * off;
            if (o2 >= best) break;
            int du = (tile[(yloc + off) * CP_LDSTR + c] >> shift) & 0xffff;
            int dl = (tile[(yloc - off) * CP_LDSTR + c] >> shift) & 0xffff;
            best = min(best, o2 + du * du);
            best = min(best, o2 + dl * dl);
        }
        int gy = y0 + yc;
        if (off == CP_HALO + 1) {             // rare: window exceeds halo
            for (; off < 512; ++off) {
                int o2 = off * off;
                if (o2 >= best) break;
                int ju = gy + off, jd = gy - off;
                if (ju < 512) {
                    int d = (packed[((size_t)b * 512 + ju) * 512 + x0 + c] >> shift) & 0xffff;
                    best = min(best, o2 + d * d);
                }
                if (jd >= 0) {
                    int d = (packed[((size_t)b * 512 + jd) * 512 + x0 + c] >> shift) & 0xffff;
                    best = min(best, o2 + d * d);
                }
            }
        }
        float dist = sqrtf((float)best);
        out[((size_t)b * 512 + gy) * 512 + x0 + c] = fg ? -dist : dist;
    }
}

extern "C" void kernel_launch(void* const* d_in, const int* in_sizes, int n_in,
                              void* d_out, int out_size, void* d_ws, size_t ws_size,
                              hipStream_t stream) {
    const float* mask = (const float*)d_in[0];
    float* out = (float*)d_out;
    const int total = in_sizes[0];            // B*512*512
    const int nrows = total / 512;            // B*512

    unsigned int* packed = (unsigned int*)d_ws;

    sdf_rowpass<<<nrows / 4, 256, 0, stream>>>(mask, packed);
    sdf_colpass<<<(nrows / CP_COLS) * (512 / CP_YCHUNK), 256, 0, stream>>>(packed, out);
}